// Round 2
// baseline (291.848 us; speedup 1.0000x reference)
//
#include <hip/hip_runtime.h>
#include <stdint.h>

typedef __attribute__((ext_vector_type(8))) short short8;
typedef __attribute__((ext_vector_type(4))) float float4v;

#define HW   4096
#define CC   256
#define SEQQ 32
#define BSZ  32
#define ROWS 64

// Tiled ctx layout (per batch): [s>>2][c>>4][s&3][c&15] shorts.
// s-group = 16 c-tiles x 64 = 1024 shorts, padded to 1032 (bank de-phase).
//   phase1 A-frag (ctx rows): 8 contiguous shorts (ds_read_b128)
//   phase2 A-frag (ctx^T):    8 x ds_read_u16 at immediate offsets
#define SGRP     1032
#define CTXT_SZ  (8 * SGRP)          // 8256 shorts per batch
#define PSTR_P   40                  // pL row stride (shorts)

static __device__ __forceinline__ uint16_t f2bf(float f) {
  union { float f; uint32_t u; } v; v.f = f;
  uint32_t r = v.u + 0x7FFFu + ((v.u >> 16) & 1u);
  return (uint16_t)(r >> 16);
}
static __device__ __forceinline__ float bf2f(uint16_t h) {
  union { uint32_t u; float f; } v; v.u = ((uint32_t)h) << 16;
  return v.f;
}

// ---------------------------------------------------------------------------
// Prep: ctx = context @ W (fp32 accum), split to bf16 hi/lo in TILED layout,
// plus mask -> 32-word bitmask (with storage-format autodetection).
// ---------------------------------------------------------------------------
extern "C" __global__ __launch_bounds__(256) void prep_kernel(
    const float* __restrict__ ctx_in,   // [32][32][256]
    const float* __restrict__ Wp,       // [256][256]
    const void*  __restrict__ mask,     // [32][32] unknown storage
    uint32_t* __restrict__ maskbits_ws, // [32] bitmask words
    uint16_t* __restrict__ hiT_ws,      // [32][8256] tiled bf16 hi
    uint16_t* __restrict__ loT_ws)      // [32][8256] tiled bf16 lo
{
  const int t = threadIdx.x;
  if (blockIdx.x == 256) {
    __shared__ int byteFlag;
    if (t == 0) byteFlag = 0;
    __syncthreads();
    const uint8_t* mb = (const uint8_t*)mask;
    int nz = 0;
    for (int i = t; i < 1024; i += 256)
      if ((i & 3) == 1 && mb[i] != 0) nz = 1;
    if (nz) atomicOr(&byteFlag, 1);
    __syncthreads();
    const bool byteMode = (byteFlag != 0);
    const uint32_t* mw32 = (const uint32_t*)mask;
    if (t < 32) {
      uint32_t bits = 0;
      for (int s = 0; s < 32; ++s) {
        bool m = byteMode ? (mb[t * 32 + s] != 0) : (mw32[t * 32 + s] != 0);
        if (m) bits |= (1u << s);
      }
      maskbits_ws[t] = bits;
    }
    return;
  }

  const int r0 = blockIdx.x * 4;
  __shared__ float crow[4][CC];
  for (int i = t; i < 1024; i += 256)
    crow[i >> 8][i & 255] = ctx_in[(size_t)r0 * CC + i];
  __syncthreads();

  const int j  = t >> 6;
  const int c4 = (t & 63) << 2;
  float4v acc = {0.f, 0.f, 0.f, 0.f};
  #pragma unroll 8
  for (int d = 0; d < CC; ++d) {
    float s = crow[j][d];
    const float4 wv = *(const float4*)&Wp[(size_t)d * CC + c4];
    acc[0] += s * wv.x; acc[1] += s * wv.y;
    acc[2] += s * wv.z; acc[3] += s * wv.w;
  }

  const int row = r0 + j, bb = row >> 5, ss = row & 31;
  const size_t base = (size_t)bb * CTXT_SZ + (ss >> 2) * SGRP + (ss & 3) * 16;
  #pragma unroll
  for (int q = 0; q < 4; ++q) {
    const int c = c4 + q;
    const float v = acc[q];
    const uint16_t h  = f2bf(v);
    const uint16_t lo = f2bf(v - bf2f(h));
    const size_t idx = base + (c >> 4) * 64 + (c & 15);
    hiT_ws[idx] = h;
    loT_ws[idx] = lo;
  }
}

// ---------------------------------------------------------------------------
// Main fused kernel. Key change vs prior round: MFMA operands SWAPPED in both
// phases (A/B frag layouts are symmetric, so swap = transposed D). Each lane
// now owns consecutive elements of ONE output row:
//   phase1: lane holds 8 logits of row n=nbase+l15 -> softmax = 7 fmax + 2
//           shuffles; out1 = 2 dwordx4 stores; pL = 2 ds_write_b64.
//   phase2: lane holds 4 consecutive channels -> out0 = 16 dwordx4 stores.
// Phase-1 x loads fully hoisted (16 dwordx4 in flight) to kill the 8-step
// serial load-latency chain.
// ---------------------------------------------------------------------------
extern "C" __global__ __launch_bounds__(256, 2) void attn_main(
    const float* __restrict__ x,        // [32][4096][256]
    const uint8_t* __restrict__ ws,
    float* __restrict__ out0,           // weighted_context [32][4096][256]
    float* __restrict__ out1)           // word_attn        [32][4096][32]
{
  const uint32_t* maskbits_ws = (const uint32_t*)ws;
  const uint16_t* hiT_ws = (const uint16_t*)(ws + 128);
  const uint16_t* loT_ws = hiT_ws + (size_t)BSZ * CTXT_SZ;

  __shared__ __align__(16) uint16_t hiT[CTXT_SZ];      // 16512 B
  __shared__ __align__(16) uint16_t loT[CTXT_SZ];      // 16512 B
  __shared__ __align__(16) uint16_t pL[ROWS * PSTR_P]; // 5120 B
  __shared__ uint32_t maskW[32];

  const int tid = threadIdx.x;
  const int b   = blockIdx.y;
  const int n0  = blockIdx.x * ROWS;

  // ---- stage tiled ctx + mask ----
  {
    const uint4* sHi = (const uint4*)(hiT_ws + (size_t)b * CTXT_SZ);
    const uint4* sLo = (const uint4*)(loT_ws + (size_t)b * CTXT_SZ);
    uint4* dHi = (uint4*)hiT;
    uint4* dLo = (uint4*)loT;
    #pragma unroll
    for (int k = 0; k < 4; ++k) {
      dHi[tid + k * 256] = sHi[tid + k * 256];
      dLo[tid + k * 256] = sLo[tid + k * 256];
    }
    if (tid < 8) { dHi[1024 + tid] = sHi[1024 + tid]; dLo[1024 + tid] = sLo[1024 + tid]; }
    if (tid < 32) maskW[tid] = maskbits_ws[tid];
  }
  __syncthreads();

  const int w    = tid >> 6;
  const int lane = tid & 63;
  const int l15  = lane & 15;
  const int quad = lane >> 4;
  const int nbase = n0 + w * 16;

  // ---- phase 1: S^T tiles via swapped split-bf16 MFMA ----
  float4v acc0 = {0.f, 0.f, 0.f, 0.f};   // s = quad*4 + r
  float4v acc1 = {0.f, 0.f, 0.f, 0.f};   // s = 16 + quad*4 + r
  const float* xrow = x + ((size_t)b * HW + nbase + l15) * CC + quad * 8;
  const int sbase = (l15 >> 2) * SGRP + (l15 & 3) * 16 + (quad >> 1) * 64 + (quad & 1) * 8;

  // hoist ALL x loads (16 dwordx4 in flight; static indexing -> registers)
  float4 xa[8], xb[8];
  #pragma unroll
  for (int k0 = 0; k0 < 8; ++k0) {
    xa[k0] = *(const float4*)(xrow + k0 * 32);
    xb[k0] = *(const float4*)(xrow + k0 * 32 + 4);
  }

  #pragma unroll
  for (int k0 = 0; k0 < 8; ++k0) {
    float xv[8] = {xa[k0].x, xa[k0].y, xa[k0].z, xa[k0].w,
                   xb[k0].x, xb[k0].y, xb[k0].z, xb[k0].w};
    short8 ah, al;
    #pragma unroll
    for (int jj = 0; jj < 8; ++jj) {
      uint32_t u = __float_as_uint(xv[jj]);
      ah[jj] = (short)(u >> 16);                              // trunc hi
      float r = xv[jj] - __uint_as_float(u & 0xFFFF0000u);    // exact residual
      al[jj] = (short)(__float_as_uint(r) >> 16);             // trunc lo
    }
    const int ka = sbase + k0 * 128;
    short8 bh0 = *(const short8*)&hiT[ka];
    short8 bl0 = *(const short8*)&loT[ka];
    short8 bh1 = *(const short8*)&hiT[ka + 4 * SGRP];
    short8 bl1 = *(const short8*)&loT[ka + 4 * SGRP];
    // swapped: A = ctx rows (s), B = x rows (n) -> D[s][n]
    acc0 = __builtin_amdgcn_mfma_f32_16x16x32_bf16(bh0, ah, acc0, 0, 0, 0);
    acc0 = __builtin_amdgcn_mfma_f32_16x16x32_bf16(bl0, ah, acc0, 0, 0, 0);
    acc0 = __builtin_amdgcn_mfma_f32_16x16x32_bf16(bh0, al, acc0, 0, 0, 0);
    acc1 = __builtin_amdgcn_mfma_f32_16x16x32_bf16(bh1, ah, acc1, 0, 0, 0);
    acc1 = __builtin_amdgcn_mfma_f32_16x16x32_bf16(bl1, ah, acc1, 0, 0, 0);
    acc1 = __builtin_amdgcn_mfma_f32_16x16x32_bf16(bh1, al, acc1, 0, 0, 0);
  }

  // ---- softmax: lane owns row n = nbase + l15, 8 of its 32 logits ----
  {
    const int n = nbase + l15;
    const uint32_t mwd = maskW[n & 31];
    float v[8];
    #pragma unroll
    for (int r = 0; r < 4; ++r) {
      v[r]     = (mwd & (1u << (quad * 4 + r)))      ? -1e30f : acc0[r];
      v[4 + r] = (mwd & (1u << (16 + quad * 4 + r))) ? -1e30f : acc1[r];
    }
    float mx = v[0];
    #pragma unroll
    for (int j = 1; j < 8; ++j) mx = fmaxf(mx, v[j]);
    mx = fmaxf(mx, __shfl_xor(mx, 16, 64));
    mx = fmaxf(mx, __shfl_xor(mx, 32, 64));
    float e[8], sm = 0.f;
    #pragma unroll
    for (int j = 0; j < 8; ++j) { e[j] = __expf(v[j] - mx); sm += e[j]; }
    sm += __shfl_xor(sm, 16, 64);
    sm += __shfl_xor(sm, 32, 64);
    const float inv = 1.0f / sm;
    float p[8];
    #pragma unroll
    for (int j = 0; j < 8; ++j) p[j] = e[j] * inv;

    float* o1row = out1 + ((size_t)b * HW + n) * SEQQ;
    *(float4*)(o1row + quad * 4)      = make_float4(p[0], p[1], p[2], p[3]);
    *(float4*)(o1row + 16 + quad * 4) = make_float4(p[4], p[5], p[6], p[7]);

    uint32_t w0 = (uint32_t)f2bf(p[0]) | ((uint32_t)f2bf(p[1]) << 16);
    uint32_t w1 = (uint32_t)f2bf(p[2]) | ((uint32_t)f2bf(p[3]) << 16);
    uint32_t w2 = (uint32_t)f2bf(p[4]) | ((uint32_t)f2bf(p[5]) << 16);
    uint32_t w3 = (uint32_t)f2bf(p[6]) | ((uint32_t)f2bf(p[7]) << 16);
    uint16_t* prow = &pL[(w * 16 + l15) * PSTR_P];
    *(uint2*)(prow + quad * 4)      = make_uint2(w0, w1);
    *(uint2*)(prow + 16 + quad * 4) = make_uint2(w2, w3);
  }
  // NO barrier: pL rows of this wave are written and read by the SAME wave.

  // ---- phase 2: O tiles via swapped MFMA: A = ctx^T gather, B = P ----
  // lane -> row n = nbase + l15, channels ct*16 + quad*4 .. +3  (dwordx4!)
  short8 pa = *(const short8*)&pL[(w * 16 + l15) * PSTR_P + quad * 8];
  const int cbase = quad * 2 * SGRP + l15;
  float* orow = out0 + ((size_t)b * HW + nbase + l15) * CC;
  #pragma unroll
  for (int ct = 0; ct < 16; ++ct) {
    short8 bfr;
    #pragma unroll
    for (int jj = 0; jj < 8; ++jj)
      bfr[jj] = (short)hiT[cbase + (jj >> 2) * SGRP + ct * 64 + (jj & 3) * 16];
    float4v z = {0.f, 0.f, 0.f, 0.f};
    float4v d = __builtin_amdgcn_mfma_f32_16x16x32_bf16(bfr, pa, z, 0, 0, 0);
    *(float4*)(orow + ct * 16 + quad * 4) = make_float4(d[0], d[1], d[2], d[3]);
  }
}

// ---------------------------------------------------------------------------
extern "C" void kernel_launch(void* const* d_in, const int* in_sizes, int n_in,
                              void* d_out, int out_size, void* d_ws, size_t ws_size,
                              hipStream_t stream) {
  const float* x      = (const float*)d_in[0];
  // d_in[1] = sentence (unused by reference call())
  const float* ctx_in = (const float*)d_in[2];
  const void*  mask   = d_in[3];
  const float* Wp     = (const float*)d_in[4];

  float* out0 = (float*)d_out;                       // [32][4096][256]
  float* out1 = out0 + (size_t)BSZ * HW * CC;        // [32][4096][32]

  uint8_t*  ws          = (uint8_t*)d_ws;
  uint32_t* maskbits_ws = (uint32_t*)ws;                         // 128 B
  uint16_t* hiT_ws      = (uint16_t*)(ws + 128);                 // 528384 B
  uint16_t* loT_ws      = hiT_ws + (size_t)BSZ * CTXT_SZ;        // 528384 B

  prep_kernel<<<257, 256, 0, stream>>>(ctx_in, Wp, mask, maskbits_ws,
                                       hiT_ws, loT_ws);
  attn_main<<<dim3(HW / ROWS, BSZ), 256, 0, stream>>>(x, ws, out0, out1);
}

// Round 3
// 284.155 us; speedup vs baseline: 1.0271x; 1.0271x over previous
//
#include <hip/hip_runtime.h>
#include <stdint.h>

typedef __attribute__((ext_vector_type(8))) short short8;
typedef __attribute__((ext_vector_type(4))) float float4v;

#define HW   4096
#define CC   256
#define SEQQ 32
#define BSZ  32
#define RPB  128   // rows per block (4 waves x 32 rows)

// Tiled ctx layout (per batch): [s>>2][c>>4][s&3][c&15] shorts.
// s-group = 16 c-tiles x 64 = 1024 shorts, padded to 1032 (bank de-phase).
//   phase1 A-frag (ctx rows): 8 contiguous shorts (ds_read_b128)
//   phase2 A-frag (ctx^T):    8 x ds_read_u16 at immediate offsets
#define SGRP     1032
#define CTXT_SZ  (8 * SGRP)          // 8256 shorts per batch
#define PSTR_P   40                  // pL row stride (shorts)

static __device__ __forceinline__ uint16_t f2bf(float f) {
  union { float f; uint32_t u; } v; v.f = f;
  uint32_t r = v.u + 0x7FFFu + ((v.u >> 16) & 1u);
  return (uint16_t)(r >> 16);
}
static __device__ __forceinline__ float bf2f(uint16_t h) {
  union { uint32_t u; float f; } v; v.u = ((uint32_t)h) << 16;
  return v.f;
}

// ---------------------------------------------------------------------------
// Prep: ctx = context @ W (fp32 accum), split to bf16 hi/lo in TILED layout,
// plus mask -> 32-word bitmask (with storage-format autodetection).
// ---------------------------------------------------------------------------
extern "C" __global__ __launch_bounds__(256) void prep_kernel(
    const float* __restrict__ ctx_in,   // [32][32][256]
    const float* __restrict__ Wp,       // [256][256]
    const void*  __restrict__ mask,     // [32][32] unknown storage
    uint32_t* __restrict__ maskbits_ws, // [32] bitmask words
    uint16_t* __restrict__ hiT_ws,      // [32][8256] tiled bf16 hi
    uint16_t* __restrict__ loT_ws)      // [32][8256] tiled bf16 lo
{
  const int t = threadIdx.x;
  if (blockIdx.x == 256) {
    __shared__ int byteFlag;
    if (t == 0) byteFlag = 0;
    __syncthreads();
    const uint8_t* mb = (const uint8_t*)mask;
    int nz = 0;
    for (int i = t; i < 1024; i += 256)
      if ((i & 3) == 1 && mb[i] != 0) nz = 1;
    if (nz) atomicOr(&byteFlag, 1);
    __syncthreads();
    const bool byteMode = (byteFlag != 0);
    const uint32_t* mw32 = (const uint32_t*)mask;
    if (t < 32) {
      uint32_t bits = 0;
      for (int s = 0; s < 32; ++s) {
        bool m = byteMode ? (mb[t * 32 + s] != 0) : (mw32[t * 32 + s] != 0);
        if (m) bits |= (1u << s);
      }
      maskbits_ws[t] = bits;
    }
    return;
  }

  const int r0 = blockIdx.x * 4;
  __shared__ float crow[4][CC];
  for (int i = t; i < 1024; i += 256)
    crow[i >> 8][i & 255] = ctx_in[(size_t)r0 * CC + i];
  __syncthreads();

  const int j  = t >> 6;
  const int c4 = (t & 63) << 2;
  float4v acc = {0.f, 0.f, 0.f, 0.f};
  #pragma unroll 8
  for (int d = 0; d < CC; ++d) {
    float s = crow[j][d];
    const float4 wv = *(const float4*)&Wp[(size_t)d * CC + c4];
    acc[0] += s * wv.x; acc[1] += s * wv.y;
    acc[2] += s * wv.z; acc[3] += s * wv.w;
  }

  const int row = r0 + j, bb = row >> 5, ss = row & 31;
  const size_t base = (size_t)bb * CTXT_SZ + (ss >> 2) * SGRP + (ss & 3) * 16;
  #pragma unroll
  for (int q = 0; q < 4; ++q) {
    const int c = c4 + q;
    const float v = acc[q];
    const uint16_t h  = f2bf(v);
    const uint16_t lo = f2bf(v - bf2f(h));
    const size_t idx = base + (c >> 4) * 64 + (c & 15);
    hiT_ws[idx] = h;
    loT_ws[idx] = lo;
  }
}

// One 16-row tile: phase1 split-bf16 MFMA (swapped operands), softmax with
// lane-owns-row layout, out1 + pL, then phase2 O = ctx^T x P with dwordx4 out.
#define COMPUTE_TILE(XA, XB, TBASE)                                           \
  {                                                                           \
    float4v acc0 = {0.f, 0.f, 0.f, 0.f};                                      \
    float4v acc1 = {0.f, 0.f, 0.f, 0.f};                                      \
    _Pragma("unroll")                                                         \
    for (int k0 = 0; k0 < 8; ++k0) {                                          \
      float xv[8] = {XA[k0].x, XA[k0].y, XA[k0].z, XA[k0].w,                  \
                     XB[k0].x, XB[k0].y, XB[k0].z, XB[k0].w};                 \
      short8 ah, al;                                                          \
      _Pragma("unroll")                                                       \
      for (int jj = 0; jj < 8; ++jj) {                                        \
        uint32_t u = __float_as_uint(xv[jj]);                                 \
        ah[jj] = (short)(u >> 16);                                            \
        float rr = xv[jj] - __uint_as_float(u & 0xFFFF0000u);                 \
        al[jj] = (short)(__float_as_uint(rr) >> 16);                          \
      }                                                                       \
      const int ka = sbase + k0 * 128;                                        \
      short8 bh0 = *(const short8*)&hiT[ka];                                  \
      short8 bl0 = *(const short8*)&loT[ka];                                  \
      short8 bh1 = *(const short8*)&hiT[ka + 4 * SGRP];                       \
      short8 bl1 = *(const short8*)&loT[ka + 4 * SGRP];                       \
      acc0 = __builtin_amdgcn_mfma_f32_16x16x32_bf16(bh0, ah, acc0, 0, 0, 0); \
      acc0 = __builtin_amdgcn_mfma_f32_16x16x32_bf16(bl0, ah, acc0, 0, 0, 0); \
      acc0 = __builtin_amdgcn_mfma_f32_16x16x32_bf16(bh0, al, acc0, 0, 0, 0); \
      acc1 = __builtin_amdgcn_mfma_f32_16x16x32_bf16(bh1, ah, acc1, 0, 0, 0); \
      acc1 = __builtin_amdgcn_mfma_f32_16x16x32_bf16(bl1, ah, acc1, 0, 0, 0); \
      acc1 = __builtin_amdgcn_mfma_f32_16x16x32_bf16(bh1, al, acc1, 0, 0, 0); \
    }                                                                         \
    const int n = (TBASE) + l15;                                              \
    const uint32_t mwd = maskW[n & 31];                                       \
    float v[8];                                                               \
    _Pragma("unroll")                                                         \
    for (int r = 0; r < 4; ++r) {                                             \
      v[r]     = (mwd & (1u << (quad * 4 + r)))      ? -1e30f : acc0[r];      \
      v[4 + r] = (mwd & (1u << (16 + quad * 4 + r))) ? -1e30f : acc1[r];      \
    }                                                                         \
    float mx = v[0];                                                          \
    _Pragma("unroll")                                                         \
    for (int jq = 1; jq < 8; ++jq) mx = fmaxf(mx, v[jq]);                     \
    mx = fmaxf(mx, __shfl_xor(mx, 16, 64));                                   \
    mx = fmaxf(mx, __shfl_xor(mx, 32, 64));                                   \
    float e[8], sm = 0.f;                                                     \
    _Pragma("unroll")                                                         \
    for (int jq = 0; jq < 8; ++jq) { e[jq] = __expf(v[jq] - mx); sm += e[jq]; } \
    sm += __shfl_xor(sm, 16, 64);                                             \
    sm += __shfl_xor(sm, 32, 64);                                             \
    const float inv = 1.0f / sm;                                              \
    float p[8];                                                               \
    _Pragma("unroll")                                                         \
    for (int jq = 0; jq < 8; ++jq) p[jq] = e[jq] * inv;                       \
    float* o1row = out1 + ((size_t)b * HW + n) * SEQQ;                        \
    *(float4*)(o1row + quad * 4)      = make_float4(p[0], p[1], p[2], p[3]);  \
    *(float4*)(o1row + 16 + quad * 4) = make_float4(p[4], p[5], p[6], p[7]);  \
    uint32_t w0 = (uint32_t)f2bf(p[0]) | ((uint32_t)f2bf(p[1]) << 16);        \
    uint32_t w1 = (uint32_t)f2bf(p[2]) | ((uint32_t)f2bf(p[3]) << 16);        \
    uint32_t w2 = (uint32_t)f2bf(p[4]) | ((uint32_t)f2bf(p[5]) << 16);        \
    uint32_t w3 = (uint32_t)f2bf(p[6]) | ((uint32_t)f2bf(p[7]) << 16);        \
    uint16_t* prow = &pL[(w * 16 + l15) * PSTR_P];                            \
    *(uint2*)(prow + quad * 4)      = make_uint2(w0, w1);                     \
    *(uint2*)(prow + 16 + quad * 4) = make_uint2(w2, w3);                     \
    short8 pa = *(const short8*)&pL[(w * 16 + l15) * PSTR_P + quad * 8];      \
    float* orow = out0 + ((size_t)b * HW + n) * CC;                           \
    _Pragma("unroll")                                                         \
    for (int ct = 0; ct < 16; ++ct) {                                         \
      short8 bfr;                                                             \
      _Pragma("unroll")                                                       \
      for (int jj = 0; jj < 8; ++jj)                                          \
        bfr[jj] = (short)hiT[cbase + (jj >> 2) * SGRP + ct * 64 + (jj & 3) * 16]; \
      float4v z = {0.f, 0.f, 0.f, 0.f};                                       \
      float4v d = __builtin_amdgcn_mfma_f32_16x16x32_bf16(bfr, pa, z, 0, 0, 0); \
      *(float4*)(orow + ct * 16 + quad * 4) = make_float4(d[0], d[1], d[2], d[3]); \
    }                                                                         \
  }

// ---------------------------------------------------------------------------
// Main fused kernel. Round-3 change: real memory-level parallelism.
// Wave owns 32 rows = 2 tiles. Issue order: staging loads -> ALL tile-0 x
// loads -> memory-clobber (pins loads: cannot sink below) -> LDS writes ->
// barrier (single merged vmcnt drain) -> ALL tile-1 x loads -> clobber ->
// compute tile0 (no global waits) -> compute tile1 (loads hidden under t0).
// ---------------------------------------------------------------------------
extern "C" __global__ __launch_bounds__(256, 2) void attn_main(
    const float* __restrict__ x,        // [32][4096][256]
    const uint8_t* __restrict__ ws,
    float* __restrict__ out0,           // weighted_context [32][4096][256]
    float* __restrict__ out1)           // word_attn        [32][4096][32]
{
  const uint32_t* maskbits_ws = (const uint32_t*)ws;
  const uint16_t* hiT_ws = (const uint16_t*)(ws + 128);
  const uint16_t* loT_ws = hiT_ws + (size_t)BSZ * CTXT_SZ;

  __shared__ __align__(16) uint16_t hiT[CTXT_SZ];      // 16512 B
  __shared__ __align__(16) uint16_t loT[CTXT_SZ];      // 16512 B
  __shared__ __align__(16) uint16_t pL[64 * PSTR_P];   // 5120 B
  __shared__ uint32_t maskW[32];

  const int tid = threadIdx.x;
  const int b   = blockIdx.y;
  const int n0  = blockIdx.x * RPB;

  const int w    = tid >> 6;
  const int lane = tid & 63;
  const int l15  = lane & 15;
  const int quad = lane >> 4;
  const int nwave = n0 + w * 32;

  const uint4* sHi = (const uint4*)(hiT_ws + (size_t)b * CTXT_SZ);
  const uint4* sLo = (const uint4*)(loT_ws + (size_t)b * CTXT_SZ);

  // ---- issue staging loads (regs) ----
  uint4 hS[4], lS[4];
  #pragma unroll
  for (int k = 0; k < 4; ++k) {
    hS[k] = sHi[tid + k * 256];
    lS[k] = sLo[tid + k * 256];
  }

  // ---- issue ALL tile-0 x loads (16 dwordx4 in flight) ----
  const float* xrow0 = x + ((size_t)b * HW + nwave + l15) * CC + quad * 8;
  float4 xa0[8], xb0[8];
  #pragma unroll
  for (int k0 = 0; k0 < 8; ++k0) {
    xa0[k0] = *(const float4*)(xrow0 + k0 * 32);
    xb0[k0] = *(const float4*)(xrow0 + k0 * 32 + 4);
  }
  asm volatile("" ::: "memory");   // pin: loads above may not sink below

  // ---- LDS writes + barrier (drains all outstanding loads at once) ----
  {
    uint4* dHi = (uint4*)hiT;
    uint4* dLo = (uint4*)loT;
    #pragma unroll
    for (int k = 0; k < 4; ++k) {
      dHi[tid + k * 256] = hS[k];
      dLo[tid + k * 256] = lS[k];
    }
    if (tid < 8) { dHi[1024 + tid] = sHi[1024 + tid]; dLo[1024 + tid] = sLo[1024 + tid]; }
    if (tid < 32) maskW[tid] = maskbits_ws[tid];
  }
  __syncthreads();

  // ---- issue ALL tile-1 x loads; latency hides under tile-0 compute ----
  const float* xrow1 = xrow0 + 16 * CC;
  float4 xa1[8], xb1[8];
  #pragma unroll
  for (int k0 = 0; k0 < 8; ++k0) {
    xa1[k0] = *(const float4*)(xrow1 + k0 * 32);
    xb1[k0] = *(const float4*)(xrow1 + k0 * 32 + 4);
  }
  asm volatile("" ::: "memory");   // pin: tile-1 loads issue before t0 compute

  const int sbase = (l15 >> 2) * SGRP + (l15 & 3) * 16 + (quad >> 1) * 64 + (quad & 1) * 8;
  const int cbase = quad * 2 * SGRP + l15;

  COMPUTE_TILE(xa0, xb0, nwave);
  COMPUTE_TILE(xa1, xb1, nwave + 16);
}

// ---------------------------------------------------------------------------
extern "C" void kernel_launch(void* const* d_in, const int* in_sizes, int n_in,
                              void* d_out, int out_size, void* d_ws, size_t ws_size,
                              hipStream_t stream) {
  const float* x      = (const float*)d_in[0];
  // d_in[1] = sentence (unused by reference call())
  const float* ctx_in = (const float*)d_in[2];
  const void*  mask   = d_in[3];
  const float* Wp     = (const float*)d_in[4];

  float* out0 = (float*)d_out;                       // [32][4096][256]
  float* out1 = out0 + (size_t)BSZ * HW * CC;        // [32][4096][32]

  uint8_t*  ws          = (uint8_t*)d_ws;
  uint32_t* maskbits_ws = (uint32_t*)ws;                         // 128 B
  uint16_t* hiT_ws      = (uint16_t*)(ws + 128);                 // 528384 B
  uint16_t* loT_ws      = hiT_ws + (size_t)BSZ * CTXT_SZ;        // 528384 B

  prep_kernel<<<257, 256, 0, stream>>>(ctx_in, Wp, mask, maskbits_ws,
                                       hiT_ws, loT_ws);
  attn_main<<<dim3(HW / RPB, BSZ), 256, 0, stream>>>(x, ws, out0, out1);
}

// Round 4
// 281.105 us; speedup vs baseline: 1.0382x; 1.0109x over previous
//
#include <hip/hip_runtime.h>
#include <stdint.h>

typedef __attribute__((ext_vector_type(8))) short short8;
typedef __attribute__((ext_vector_type(4))) float float4v;

#define HW   4096
#define CC   256
#define SEQQ 32
#define BSZ  32
#define RPB  128   // rows per block (4 waves x 32 rows)

// Tiled ctx layout (per batch): [s>>2][c>>4][s&3][c&15] shorts.
// s-group = 16 c-tiles x 64 = 1024 shorts, padded to 1032 (bank de-phase).
#define SGRP     1032
#define CTXT_SZ  (8 * SGRP)          // 8256 shorts per batch
#define PSTR_P   40                  // pL row stride (shorts)

static __device__ __forceinline__ uint16_t f2bf(float f) {
  union { float f; uint32_t u; } v; v.f = f;
  uint32_t r = v.u + 0x7FFFu + ((v.u >> 16) & 1u);
  return (uint16_t)(r >> 16);
}
static __device__ __forceinline__ float bf2f(uint16_t h) {
  union { uint32_t u; float f; } v; v.u = ((uint32_t)h) << 16;
  return v.f;
}

// ---------------------------------------------------------------------------
// Prep: ctx = context @ W (fp32 accum), split to bf16 hi/lo in TILED layout,
// plus mask -> 32-word bitmask (with storage-format autodetection).
// ---------------------------------------------------------------------------
extern "C" __global__ __launch_bounds__(256) void prep_kernel(
    const float* __restrict__ ctx_in,   // [32][32][256]
    const float* __restrict__ Wp,       // [256][256]
    const void*  __restrict__ mask,     // [32][32] unknown storage
    uint32_t* __restrict__ maskbits_ws, // [32] bitmask words
    uint16_t* __restrict__ hiT_ws,      // [32][8256] tiled bf16 hi
    uint16_t* __restrict__ loT_ws)      // [32][8256] tiled bf16 lo
{
  const int t = threadIdx.x;
  if (blockIdx.x == 256) {
    __shared__ int byteFlag;
    if (t == 0) byteFlag = 0;
    __syncthreads();
    const uint8_t* mb = (const uint8_t*)mask;
    int nz = 0;
    for (int i = t; i < 1024; i += 256)
      if ((i & 3) == 1 && mb[i] != 0) nz = 1;
    if (nz) atomicOr(&byteFlag, 1);
    __syncthreads();
    const bool byteMode = (byteFlag != 0);
    const uint32_t* mw32 = (const uint32_t*)mask;
    if (t < 32) {
      uint32_t bits = 0;
      for (int s = 0; s < 32; ++s) {
        bool m = byteMode ? (mb[t * 32 + s] != 0) : (mw32[t * 32 + s] != 0);
        if (m) bits |= (1u << s);
      }
      maskbits_ws[t] = bits;
    }
    return;
  }

  const int r0 = blockIdx.x * 4;
  __shared__ float crow[4][CC];
  for (int i = t; i < 1024; i += 256)
    crow[i >> 8][i & 255] = ctx_in[(size_t)r0 * CC + i];
  __syncthreads();

  const int j  = t >> 6;
  const int c4 = (t & 63) << 2;
  float4v acc = {0.f, 0.f, 0.f, 0.f};
  #pragma unroll 8
  for (int d = 0; d < CC; ++d) {
    float s = crow[j][d];
    const float4 wv = *(const float4*)&Wp[(size_t)d * CC + c4];
    acc[0] += s * wv.x; acc[1] += s * wv.y;
    acc[2] += s * wv.z; acc[3] += s * wv.w;
  }

  const int row = r0 + j, bb = row >> 5, ss = row & 31;
  const size_t base = (size_t)bb * CTXT_SZ + (ss >> 2) * SGRP + (ss & 3) * 16;
  #pragma unroll
  for (int q = 0; q < 4; ++q) {
    const int c = c4 + q;
    const float v = acc[q];
    const uint16_t h  = f2bf(v);
    const uint16_t lo = f2bf(v - bf2f(h));
    const size_t idx = base + (c >> 4) * 64 + (c & 15);
    hiT_ws[idx] = h;
    loT_ws[idx] = lo;
  }
}

// One 16-row tile. Phase1: split-bf16 MFMA (swapped operands). Softmax with
// lane-owns-row layout. NEW: out1 and out0 go through a per-wave XOR-swizzled
// LDS transpose so every global store instruction covers only FULL 128B
// lines (1KB contiguous for out1, 4x256B full-line segments for out0) --
// eliminating the 64B partial-sector RMW that capped write throughput.
#define COMPUTE_TILE(XA, XB, TBASE)                                           \
  {                                                                           \
    float4v acc0 = {0.f, 0.f, 0.f, 0.f};                                      \
    float4v acc1 = {0.f, 0.f, 0.f, 0.f};                                      \
    _Pragma("unroll")                                                         \
    for (int k0 = 0; k0 < 8; ++k0) {                                          \
      float xv[8] = {XA[k0].x, XA[k0].y, XA[k0].z, XA[k0].w,                  \
                     XB[k0].x, XB[k0].y, XB[k0].z, XB[k0].w};                 \
      short8 ah, al;                                                          \
      _Pragma("unroll")                                                       \
      for (int jj = 0; jj < 8; ++jj) {                                        \
        uint32_t u = __float_as_uint(xv[jj]);                                 \
        ah[jj] = (short)(u >> 16);                                            \
        float rr_ = xv[jj] - __uint_as_float(u & 0xFFFF0000u);                \
        al[jj] = (short)(__float_as_uint(rr_) >> 16);                         \
      }                                                                       \
      const int ka = sbase + k0 * 128;                                        \
      short8 bh0 = *(const short8*)&hiT[ka];                                  \
      short8 bl0 = *(const short8*)&loT[ka];                                  \
      short8 bh1 = *(const short8*)&hiT[ka + 4 * SGRP];                       \
      short8 bl1 = *(const short8*)&loT[ka + 4 * SGRP];                       \
      acc0 = __builtin_amdgcn_mfma_f32_16x16x32_bf16(bh0, ah, acc0, 0, 0, 0); \
      acc0 = __builtin_amdgcn_mfma_f32_16x16x32_bf16(bl0, ah, acc0, 0, 0, 0); \
      acc0 = __builtin_amdgcn_mfma_f32_16x16x32_bf16(bh0, al, acc0, 0, 0, 0); \
      acc1 = __builtin_amdgcn_mfma_f32_16x16x32_bf16(bh1, ah, acc1, 0, 0, 0); \
      acc1 = __builtin_amdgcn_mfma_f32_16x16x32_bf16(bl1, ah, acc1, 0, 0, 0); \
      acc1 = __builtin_amdgcn_mfma_f32_16x16x32_bf16(bh1, al, acc1, 0, 0, 0); \
    }                                                                         \
    const int n = (TBASE) + l15;                                              \
    const uint32_t mwd = maskW[n & 31];                                       \
    float v[8];                                                               \
    _Pragma("unroll")                                                         \
    for (int r = 0; r < 4; ++r) {                                             \
      v[r]     = (mwd & (1u << (quad * 4 + r)))      ? -1e30f : acc0[r];      \
      v[4 + r] = (mwd & (1u << (16 + quad * 4 + r))) ? -1e30f : acc1[r];      \
    }                                                                         \
    float mx = v[0];                                                          \
    _Pragma("unroll")                                                         \
    for (int jq = 1; jq < 8; ++jq) mx = fmaxf(mx, v[jq]);                     \
    mx = fmaxf(mx, __shfl_xor(mx, 16, 64));                                   \
    mx = fmaxf(mx, __shfl_xor(mx, 32, 64));                                   \
    float e[8], sm = 0.f;                                                     \
    _Pragma("unroll")                                                         \
    for (int jq = 0; jq < 8; ++jq) { e[jq] = __expf(v[jq] - mx); sm += e[jq]; } \
    sm += __shfl_xor(sm, 16, 64);                                             \
    sm += __shfl_xor(sm, 32, 64);                                             \
    const float inv = 1.0f / sm;                                              \
    float p[8];                                                               \
    _Pragma("unroll")                                                         \
    for (int jq = 0; jq < 8; ++jq) p[jq] = e[jq] * inv;                       \
    /* out1 via XOR-swizzled LDS transpose ([16][32] f32, 8 slots/row) */     \
    const int r8 = l15 & 7;                                                   \
    *(float4*)&ostW[l15 * 32 + ((quad ^ r8) << 2)] =                          \
        make_float4(p[0], p[1], p[2], p[3]);                                  \
    *(float4*)&ostW[l15 * 32 + (((4 + quad) ^ r8) << 2)] =                    \
        make_float4(p[4], p[5], p[6], p[7]);                                  \
    uint32_t w0 = (uint32_t)f2bf(p[0]) | ((uint32_t)f2bf(p[1]) << 16);        \
    uint32_t w1 = (uint32_t)f2bf(p[2]) | ((uint32_t)f2bf(p[3]) << 16);        \
    uint32_t w2 = (uint32_t)f2bf(p[4]) | ((uint32_t)f2bf(p[5]) << 16);        \
    uint32_t w3 = (uint32_t)f2bf(p[6]) | ((uint32_t)f2bf(p[7]) << 16);        \
    uint16_t* prow = &pL[(w * 16 + l15) * PSTR_P];                            \
    *(uint2*)(prow + quad * 4)      = make_uint2(w0, w1);                     \
    *(uint2*)(prow + 16 + quad * 4) = make_uint2(w2, w3);                     \
    _Pragma("unroll")                                                         \
    for (int i2 = 0; i2 < 2; ++i2) {                                          \
      const int rr = 8 * i2 + (lane >> 3);                                    \
      const int mm = lane & 7;                                                \
      float4 vv = *(const float4*)&ostW[rr * 32 + ((mm ^ (rr & 7)) << 2)];    \
      *(float4*)(out1 + ((size_t)b * HW + (TBASE) + rr) * SEQQ + mm * 4) = vv;\
    }                                                                         \
    /* phase 2: per 64-ch group, MFMA -> LDS transpose -> full-line stores */ \
    short8 pa = *(const short8*)&pL[(w * 16 + l15) * PSTR_P + quad * 8];      \
    _Pragma("unroll")                                                         \
    for (int cg = 0; cg < 4; ++cg) {                                          \
      _Pragma("unroll")                                                       \
      for (int j2 = 0; j2 < 4; ++j2) {                                        \
        const int ct = cg * 4 + j2;                                           \
        short8 bfr;                                                           \
        _Pragma("unroll")                                                     \
        for (int jj = 0; jj < 8; ++jj)                                        \
          bfr[jj] = (short)hiT[cbase + (jj >> 2) * SGRP + ct * 64 + (jj & 3) * 16]; \
        float4v z = {0.f, 0.f, 0.f, 0.f};                                     \
        float4v dd = __builtin_amdgcn_mfma_f32_16x16x32_bf16(bfr, pa, z, 0, 0, 0); \
        const int ss = j2 * 4 + quad;                                         \
        *(float4*)&ostW[l15 * 64 + ((ss ^ l15) << 2)] =                       \
            make_float4(dd[0], dd[1], dd[2], dd[3]);                          \
      }                                                                       \
      _Pragma("unroll")                                                       \
      for (int i2 = 0; i2 < 4; ++i2) {                                        \
        const int rr = 4 * i2 + (lane >> 4);                                  \
        const int mm = lane & 15;                                             \
        float4 vv = *(const float4*)&ostW[rr * 64 + ((mm ^ rr) << 2)];        \
        *(float4*)(out0 + ((size_t)b * HW + (TBASE) + rr) * CC + cg * 64 + mm * 4) = vv; \
      }                                                                       \
    }                                                                         \
  }

// ---------------------------------------------------------------------------
// Main fused kernel. Round-4 change: full-line-only global stores via
// per-wave XOR-swizzled LDS transpose epilogues (no new barriers).
// ---------------------------------------------------------------------------
extern "C" __global__ __launch_bounds__(256, 2) void attn_main(
    const float* __restrict__ x,        // [32][4096][256]
    const uint8_t* __restrict__ ws,
    float* __restrict__ out0,           // weighted_context [32][4096][256]
    float* __restrict__ out1)           // word_attn        [32][4096][32]
{
  const uint32_t* maskbits_ws = (const uint32_t*)ws;
  const uint16_t* hiT_ws = (const uint16_t*)(ws + 128);
  const uint16_t* loT_ws = hiT_ws + (size_t)BSZ * CTXT_SZ;

  __shared__ __align__(16) uint16_t hiT[CTXT_SZ];      // 16512 B
  __shared__ __align__(16) uint16_t loT[CTXT_SZ];      // 16512 B
  __shared__ __align__(16) uint16_t pL[64 * PSTR_P];   // 5120 B
  __shared__ __align__(16) float    oStgF[4 * 1024];   // 16384 B (4KB/wave)
  __shared__ uint32_t maskW[32];

  const int tid = threadIdx.x;
  const int b   = blockIdx.y;
  const int n0  = blockIdx.x * RPB;

  const int w    = tid >> 6;
  const int lane = tid & 63;
  const int l15  = lane & 15;
  const int quad = lane >> 4;
  const int nwave = n0 + w * 32;
  float* ostW = &oStgF[w * 1024];

  const uint4* sHi = (const uint4*)(hiT_ws + (size_t)b * CTXT_SZ);
  const uint4* sLo = (const uint4*)(loT_ws + (size_t)b * CTXT_SZ);

  // ---- issue staging loads (regs) ----
  uint4 hS[4], lS[4];
  #pragma unroll
  for (int k = 0; k < 4; ++k) {
    hS[k] = sHi[tid + k * 256];
    lS[k] = sLo[tid + k * 256];
  }

  // ---- issue ALL tile-0 x loads (16 dwordx4 in flight) ----
  const float* xrow0 = x + ((size_t)b * HW + nwave + l15) * CC + quad * 8;
  float4 xa0[8], xb0[8];
  #pragma unroll
  for (int k0 = 0; k0 < 8; ++k0) {
    xa0[k0] = *(const float4*)(xrow0 + k0 * 32);
    xb0[k0] = *(const float4*)(xrow0 + k0 * 32 + 4);
  }
  asm volatile("" ::: "memory");   // pin: loads above may not sink below

  // ---- LDS writes + barrier ----
  {
    uint4* dHi = (uint4*)hiT;
    uint4* dLo = (uint4*)loT;
    #pragma unroll
    for (int k = 0; k < 4; ++k) {
      dHi[tid + k * 256] = hS[k];
      dLo[tid + k * 256] = lS[k];
    }
    if (tid < 8) { dHi[1024 + tid] = sHi[1024 + tid]; dLo[1024 + tid] = sLo[1024 + tid]; }
    if (tid < 32) maskW[tid] = maskbits_ws[tid];
  }
  __syncthreads();

  // ---- issue ALL tile-1 x loads; latency hides under tile-0 compute ----
  const float* xrow1 = xrow0 + 16 * CC;
  float4 xa1[8], xb1[8];
  #pragma unroll
  for (int k0 = 0; k0 < 8; ++k0) {
    xa1[k0] = *(const float4*)(xrow1 + k0 * 32);
    xb1[k0] = *(const float4*)(xrow1 + k0 * 32 + 4);
  }
  asm volatile("" ::: "memory");   // pin: tile-1 loads issue before t0 compute

  const int sbase = (l15 >> 2) * SGRP + (l15 & 3) * 16 + (quad >> 1) * 64 + (quad & 1) * 8;
  const int cbase = quad * 2 * SGRP + l15;

  COMPUTE_TILE(xa0, xb0, nwave);
  COMPUTE_TILE(xa1, xb1, nwave + 16);
}

// ---------------------------------------------------------------------------
extern "C" void kernel_launch(void* const* d_in, const int* in_sizes, int n_in,
                              void* d_out, int out_size, void* d_ws, size_t ws_size,
                              hipStream_t stream) {
  const float* x      = (const float*)d_in[0];
  // d_in[1] = sentence (unused by reference call())
  const float* ctx_in = (const float*)d_in[2];
  const void*  mask   = d_in[3];
  const float* Wp     = (const float*)d_in[4];

  float* out0 = (float*)d_out;                       // [32][4096][256]
  float* out1 = out0 + (size_t)BSZ * HW * CC;        // [32][4096][32]

  uint8_t*  ws          = (uint8_t*)d_ws;
  uint32_t* maskbits_ws = (uint32_t*)ws;                         // 128 B
  uint16_t* hiT_ws      = (uint16_t*)(ws + 128);                 // 528384 B
  uint16_t* loT_ws      = hiT_ws + (size_t)BSZ * CTXT_SZ;        // 528384 B

  prep_kernel<<<257, 256, 0, stream>>>(ctx_in, Wp, mask, maskbits_ws,
                                       hiT_ws, loT_ws);
  attn_main<<<dim3(HW / RPB, BSZ), 256, 0, stream>>>(x, ws, out0, out1);
}